// Round 2
// baseline (893.853 us; speedup 1.0000x reference)
//
#include <hip/hip_runtime.h>

typedef unsigned short u16;
typedef __bf16 bf16x8 __attribute__((ext_vector_type(8)));
typedef float f32x4 __attribute__((ext_vector_type(4)));

typedef const __attribute__((address_space(1))) void gv_t;
typedef __attribute__((address_space(3))) void lv_t;

__device__ __forceinline__ float b2f(u16 u) {
    union { unsigned int i; float f; } v; v.i = ((unsigned int)u) << 16; return v.f;
}
__device__ __forceinline__ u16 f2b(float f) {
    union { unsigned int i; float f; } v; v.f = f;
    unsigned int b = v.i;
    return (u16)((b + 0x7FFFu + ((b >> 16) & 1u)) >> 16);
}

// Hamilton product tables: out component p, input component q -> weight index / sign
__constant__ int   c_qidx[16] = {0,1,2,3, 1,0,3,2, 2,3,0,1, 3,2,1,0};
__constant__ float c_qsgn[16] = {1,-1,-1,-1, 1,1,1,-1, 1,-1,1,1, 1,1,-1,1};

// ---------------------------------------------------------------- weights ---
__global__ void build_weights(const float* __restrict__ wqkv, const float* __restrict__ wproj,
                              const float* __restrict__ wf1, const float* __restrict__ wf2,
                              const float* __restrict__ wpe,
                              u16* __restrict__ Wq, u16* __restrict__ Wp, u16* __restrict__ W1,
                              u16* __restrict__ W2, float* __restrict__ Wpe_eff)
{
    long i = (long)blockIdx.x * 256 + threadIdx.x;
    if (i < 3145728L) {  // qkv: M=3072 K=1024
        int m = (int)(i >> 10), k = (int)(i & 1023);
        int o = m >> 2, p = m & 3, c = k >> 2, q = k & 3, pq = (p << 2) | q;
        Wq[i] = f2b(c_qsgn[pq] * wqkv[c_qidx[pq] * 196608 + o * 256 + c]);
        return;
    }
    i -= 3145728L;
    if (i < 1048576L) {  // proj: 1024x1024
        int m = (int)(i >> 10), k = (int)(i & 1023);
        int o = m >> 2, p = m & 3, c = k >> 2, q = k & 3, pq = (p << 2) | q;
        Wp[i] = f2b(c_qsgn[pq] * wproj[c_qidx[pq] * 65536 + o * 256 + c]);
        return;
    }
    i -= 1048576L;
    if (i < 2097152L) {  // f1: 2048x1024
        int m = (int)(i >> 10), k = (int)(i & 1023);
        int o = m >> 2, p = m & 3, c = k >> 2, q = k & 3, pq = (p << 2) | q;
        W1[i] = f2b(c_qsgn[pq] * wf1[c_qidx[pq] * 131072 + o * 256 + c]);
        return;
    }
    i -= 2097152L;
    if (i < 2097152L) {  // f2: 1024x2048
        int m = (int)(i >> 11), k = (int)(i & 2047);
        int o = m >> 2, p = m & 3, c = k >> 2, q = k & 3, pq = (p << 2) | q;
        W2[i] = f2b(c_qsgn[pq] * wf2[c_qidx[pq] * 131072 + o * 512 + c]);
        return;
    }
    i -= 2097152L;
    if (i < 147456L) {   // pe: [g][tap][fi][of], fp32
        int g = (int)(i / 2304), r = (int)(i % 2304);
        int tap = r >> 8, r2 = r & 255;
        int fi = r2 >> 4, of = r2 & 15;
        int ol = of >> 2, p = of & 3, ci = fi >> 2, q = fi & 3, pq = (p << 2) | q;
        Wpe_eff[i] = c_qsgn[pq] * wpe[c_qidx[pq] * 9216 + (g * 4 + ol) * 36 + ci * 9 + tap];
    }
}

__global__ void zero_accum(float* __restrict__ a)
{
    a[blockIdx.x * 256 + threadIdx.x] = 0.f;
}

// ------------------------------------------------- cast + transpose of x ---
// x fp32 [b][1024][4096] -> Xt bf16 [b][4096][1024]
__global__ __launch_bounds__(256) void cast_tr(const float* __restrict__ x, u16* __restrict__ Xt)
{
    int b = blockIdx.z, mt = blockIdx.y * 64, nt = blockIdx.x * 64;
    __shared__ u16 tl[64][66];
    int t = threadIdx.x, col = t & 63;
    for (int r = 0; r < 64; r += 4) {
        int ml = r + (t >> 6);
        tl[ml][col] = f2b(x[((long)b * 1024 + mt + ml) * 4096 + nt + col]);
    }
    __syncthreads();
    for (int r = 0; r < 64; r += 4) {
        int nl = r + (t >> 6);
        Xt[((long)b * 4096 + nt + nl) * 1024 + mt + col] = tl[col][nl];
    }
}

// ------------------------------------------------------------------ GEMM ---
// C = A[M][K] x Bt[b][N][K]^T.  TROUT=false: C[b][M][N] (feature-major).
// TROUT=true: C[b][N][M] (pixel-major) via LDS epilogue transpose.
__device__ __forceinline__ void async_copy16(const u16* g, u16* l) {
    __builtin_amdgcn_global_load_lds((gv_t*)g, (lv_t*)l, 16, 0, 0);
}

template<bool TROUT>
__global__ __launch_bounds__(256) void gemm_bt(
    const u16* __restrict__ A, const u16* __restrict__ Bt, u16* __restrict__ C,
    int M, int N, int K, long strideB, long strideC)
{
    __shared__ __align__(16) u16 smem[TROUT ? 17408 : 8192];
    u16* As = smem;
    u16* Bs = smem + 4096;
    const int t = threadIdx.x;
    const int b = blockIdx.z;
    const u16* Bb = Bt + (long)b * strideB;
    const int m0 = blockIdx.y * 128, n0 = blockIdx.x * 128;
    const int lane = t & 63, w = t >> 6;
    const int row = t >> 2;            // staging row 0..63
    const int k8 = (t & 3) * 8;        // staging k offset (8 bf16 = 16B)
    const int wm = (w >> 1) * 64, wn = (w & 1) * 64;
    const int quad = lane >> 4, r16 = lane & 15;

    const u16* a_rd = As + (wm + r16) * 32 + quad * 8;
    const u16* b_rd = Bs + (wn + r16) * 32 + quad * 8;

    f32x4 acc[4][4];
#pragma unroll
    for (int i = 0; i < 4; i++)
#pragma unroll
        for (int j = 0; j < 4; j++) acc[i][j] = (f32x4){0.f, 0.f, 0.f, 0.f};

    const u16* gA0 = A + (long)(m0 + row) * K + k8;
    const u16* gA1 = A + (long)(m0 + row + 64) * K + k8;
    const u16* gB0 = Bb + (long)(n0 + row) * K + k8;
    const u16* gB1 = Bb + (long)(n0 + row + 64) * K + k8;
    u16* lA0 = As + t * 8; u16* lA1 = As + (t + 256) * 8;
    u16* lB0 = Bs + t * 8; u16* lB1 = Bs + (t + 256) * 8;

    for (int kt = 0; kt < K; kt += 32) {
        async_copy16(gA0 + kt, lA0);
        async_copy16(gA1 + kt, lA1);
        async_copy16(gB0 + kt, lB0);
        async_copy16(gB1 + kt, lB1);
        __syncthreads();
        bf16x8 bfr[4];
#pragma unroll
        for (int j = 0; j < 4; j++) bfr[j] = *(const bf16x8*)(b_rd + j * 16 * 32);
#pragma unroll
        for (int i = 0; i < 4; i++) {
            bf16x8 af = *(const bf16x8*)(a_rd + i * 16 * 32);
#pragma unroll
            for (int j = 0; j < 4; j++)
                acc[i][j] = __builtin_amdgcn_mfma_f32_16x16x32_bf16(af, bfr[j], acc[i][j], 0, 0, 0);
        }
        __syncthreads();
    }

    if (!TROUT) {
        u16* Cb = C + (long)b * strideC;
#pragma unroll
        for (int i = 0; i < 4; i++)
#pragma unroll
            for (int j = 0; j < 4; j++) {
                int mm = m0 + wm + i * 16 + quad * 4;
                int nn = n0 + wn + j * 16 + r16;
#pragma unroll
                for (int r = 0; r < 4; r++)
                    Cb[(long)(mm + r) * N + nn] = f2b(acc[i][j][r]);
            }
    } else {
        // stage 128x128 tile transposed in LDS ([n][m], pad to 136), then
        // coalesced pixel-major store: C[b][n0+n][m0+m]
        u16* Ct = smem;
#pragma unroll
        for (int i = 0; i < 4; i++)
#pragma unroll
            for (int j = 0; j < 4; j++) {
                int mm = wm + i * 16 + quad * 4;   // multiple of 4 -> 8B aligned
                int nn = wn + j * 16 + r16;
                ushort4 pk;
                pk.x = f2b(acc[i][j][0]); pk.y = f2b(acc[i][j][1]);
                pk.z = f2b(acc[i][j][2]); pk.w = f2b(acc[i][j][3]);
                *(ushort4*)(Ct + nn * 136 + mm) = pk;
            }
        __syncthreads();
        u16* Cb = C + (long)b * strideC;
        for (int rr = 0; rr < 128; rr += 16) {
            int n = rr + (t >> 4);
            int m8 = (t & 15) * 8;
            uint4 v = *(const uint4*)(Ct + n * 136 + m8);   // 272B row stride -> 16B aligned
            *(uint4*)(Cb + (long)(n0 + n) * M + m0 + m8) = v;
        }
    }
}

// ------------------------------------------------------------- attention ---
__global__ __launch_bounds__(256) void attn_kernel(const u16* __restrict__ QKV, u16* __restrict__ O)
{
    const int blk = blockIdx.x;
    const int bi = blk >> 5, h = (blk >> 2) & 7, p = blk & 3;
    const long rs = 16384;  // channel row stride (4 * 4096)
    const u16* base = QKV + (long)bi * (3072L * 4096) + (long)(h * 384 + p) * 4096;
    const int t = threadIdx.x, lane = t & 63, w = t >> 6;
    const int quad = lane >> 4, r16 = lane & 15;
    __shared__ float Sred[4][32][32];
    __shared__ float Pm[32][32];

    f32x4 acc[2][2];
#pragma unroll
    for (int i = 0; i < 2; i++)
#pragma unroll
        for (int j = 0; j < 2; j++) acc[i][j] = (f32x4){0.f, 0.f, 0.f, 0.f};

    const int nb = w * 1024 + quad * 8;
    for (int kk = 0; kk < 1024; kk += 32) {
        long off = nb + kk;
        bf16x8 q0 = *(const bf16x8*)(base + (long)r16 * rs + off);
        bf16x8 q1 = *(const bf16x8*)(base + (long)(16 + r16) * rs + off);
        bf16x8 k0 = *(const bf16x8*)(base + (long)(32 + r16) * rs + off);
        bf16x8 k1 = *(const bf16x8*)(base + (long)(48 + r16) * rs + off);
        acc[0][0] = __builtin_amdgcn_mfma_f32_16x16x32_bf16(q0, k0, acc[0][0], 0, 0, 0);
        acc[0][1] = __builtin_amdgcn_mfma_f32_16x16x32_bf16(q0, k1, acc[0][1], 0, 0, 0);
        acc[1][0] = __builtin_amdgcn_mfma_f32_16x16x32_bf16(q1, k0, acc[1][0], 0, 0, 0);
        acc[1][1] = __builtin_amdgcn_mfma_f32_16x16x32_bf16(q1, k1, acc[1][1], 0, 0, 0);
    }
#pragma unroll
    for (int i = 0; i < 2; i++)
#pragma unroll
        for (int j = 0; j < 2; j++)
#pragma unroll
            for (int r = 0; r < 4; r++)
                Sred[w][i * 16 + quad * 4 + r][j * 16 + r16] = acc[i][j][r];
    __syncthreads();
    for (int e = t; e < 1024; e += 256) {
        int c = e >> 5, d = e & 31;
        Pm[c][d] = (Sred[0][c][d] + Sred[1][c][d] + Sred[2][c][d] + Sred[3][c][d]) * 0.17677669529663687f;
    }
    __syncthreads();
    if (t < 32) {
        float mx = -1e30f;
        for (int d = 0; d < 32; d++) mx = fmaxf(mx, Pm[t][d]);
        float sum = 0.f;
        for (int d = 0; d < 32; d++) { float e = __expf(Pm[t][d] - mx); Pm[t][d] = e; sum += e; }
        float inv = 1.f / sum;
        for (int d = 0; d < 32; d++) Pm[t][d] *= inv;
    }
    __syncthreads();

    u16* Ob = O + (long)bi * (1024L * 4096) + (long)(h * 128 + p) * 4096;
    for (int nc = 0; nc < 4096; nc += 1024) {
        float v[32][4];
#pragma unroll
        for (int d = 0; d < 32; d++) {
            const u16* vp = base + (long)(64 + d) * rs + nc + 2 * t;
            unsigned int u0 = *(const unsigned int*)vp;
            unsigned int u1 = *(const unsigned int*)(vp + 512);
            v[d][0] = b2f((u16)u0); v[d][1] = b2f((u16)(u0 >> 16));
            v[d][2] = b2f((u16)u1); v[d][3] = b2f((u16)(u1 >> 16));
        }
        for (int c = 0; c < 32; c++) {
            float s0 = 0.f, s1 = 0.f, s2 = 0.f, s3 = 0.f;
            const float4* prow = (const float4*)(&Pm[c][0]);
#pragma unroll
            for (int dq = 0; dq < 8; dq++) {
                float4 pv = prow[dq];
                s0 = fmaf(pv.x, v[4*dq+0][0], s0); s1 = fmaf(pv.x, v[4*dq+0][1], s1);
                s2 = fmaf(pv.x, v[4*dq+0][2], s2); s3 = fmaf(pv.x, v[4*dq+0][3], s3);
                s0 = fmaf(pv.y, v[4*dq+1][0], s0); s1 = fmaf(pv.y, v[4*dq+1][1], s1);
                s2 = fmaf(pv.y, v[4*dq+1][2], s2); s3 = fmaf(pv.y, v[4*dq+1][3], s3);
                s0 = fmaf(pv.z, v[4*dq+2][0], s0); s1 = fmaf(pv.z, v[4*dq+2][1], s1);
                s2 = fmaf(pv.z, v[4*dq+2][2], s2); s3 = fmaf(pv.z, v[4*dq+2][3], s3);
                s0 = fmaf(pv.w, v[4*dq+3][0], s0); s1 = fmaf(pv.w, v[4*dq+3][1], s1);
                s2 = fmaf(pv.w, v[4*dq+3][2], s2); s3 = fmaf(pv.w, v[4*dq+3][3], s3);
            }
            unsigned int* op = (unsigned int*)(Ob + (long)c * 16384 + nc + 2 * t);
            op[0]   = (unsigned int)f2b(s0) | ((unsigned int)f2b(s1) << 16);
            op[256] = (unsigned int)f2b(s2) | ((unsigned int)f2b(s3) << 16);
        }
    }
}

// ------------------------------------------------------ pe conv + residual ---
// O2t[b][n][feat] = O + qconv_pe(O)
__global__ __launch_bounds__(256) void pe_kernel(const u16* __restrict__ Oin,
                                                 const float* __restrict__ Wpe,
                                                 u16* __restrict__ O2t)
{
    const int tile = blockIdx.x, g = blockIdx.y, bi = blockIdx.z;
    const int y0 = (tile >> 2) * 16, x0 = (tile & 3) * 16;
    __shared__ float tin[16][324];  // 16 feats x 18x18 halo tile
    const int t = threadIdx.x;
    const u16* Ob = Oin + (long)bi * (1024L * 4096) + (long)(g * 16) * 4096;
    for (int e = t; e < 16 * 324; e += 256) {
        int f = e / 324, rem = e % 324;
        int yy = rem / 18 - 1 + y0, xx = rem % 18 - 1 + x0;
        float v = 0.f;
        if (yy >= 0 && yy < 64 && xx >= 0 && xx < 64)
            v = b2f(Ob[(long)f * 4096 + yy * 64 + xx]);
        tin[f][rem] = v;
    }
    __syncthreads();
    const int y = t >> 4, x = t & 15;
    float acc[16];
#pragma unroll
    for (int of = 0; of < 16; of++) acc[of] = tin[of][(y + 1) * 18 + (x + 1)];  // residual
    const float* Wg = Wpe + g * 2304;
    for (int dy = 0; dy < 3; dy++)
        for (int dx = 0; dx < 3; dx++) {
            int off = (y + dy) * 18 + (x + dx);
            int tap = dy * 3 + dx;
            for (int fi = 0; fi < 16; fi++) {
                float v = tin[fi][off];
                const float* wp = Wg + (tap * 16 + fi) * 16;
#pragma unroll
                for (int of = 0; of < 16; of++) acc[of] = fmaf(wp[of], v, acc[of]);
            }
        }
    long n = (long)(y0 + y) * 64 + (x0 + x);
    unsigned int* op = (unsigned int*)(O2t + ((long)bi * 4096 + n) * 1024 + g * 16);
#pragma unroll
    for (int u = 0; u < 8; u++)
        op[u] = (unsigned int)f2b(acc[2 * u]) | ((unsigned int)f2b(acc[2 * u + 1]) << 16);
}

// ----------------------------------------- BN stats, feature-major layout ---
// One block per row m: mean/rstd over (B=4, N=4096) of bf16 [b][M][4096].
__global__ __launch_bounds__(256) void bn_stats(const u16* __restrict__ X, float* __restrict__ stats, int M)
{
    const int m = blockIdx.x, t = threadIdx.x;
    float s = 0.f, ss = 0.f;
    for (int b = 0; b < 4; b++) {
        const u16* rowp = X + ((long)b * M + m) * 4096;
        for (int pass = 0; pass < 2; pass++) {
            uint4 uv = *(const uint4*)(rowp + pass * 2048 + t * 8);
            unsigned int wsa[4] = {uv.x, uv.y, uv.z, uv.w};
#pragma unroll
            for (int u = 0; u < 4; u++) {
                float v0 = b2f((u16)wsa[u]), v1 = b2f((u16)(wsa[u] >> 16));
                s += v0 + v1; ss += v0 * v0 + v1 * v1;
            }
        }
    }
    __shared__ float rs[4], rss[4];
    for (int o = 32; o > 0; o >>= 1) { s += __shfl_down(s, o); ss += __shfl_down(ss, o); }
    if ((t & 63) == 0) { rs[t >> 6] = s; rss[t >> 6] = ss; }
    __syncthreads();
    if (t == 0) {
        float S = rs[0] + rs[1] + rs[2] + rs[3];
        float SS = rss[0] + rss[1] + rss[2] + rss[3];
        float mean = S * (1.f / 16384.f);
        float var = SS * (1.f / 16384.f) - mean * mean;
        stats[2 * m] = mean;
        stats[2 * m + 1] = rsqrtf(var + 1e-5f);
    }
}

// ------------------------------------------- X1t = cast_tr(x + BN(P)) bf16 ---
__global__ __launch_bounds__(256) void bn_add_tr(const float* __restrict__ x, const u16* __restrict__ P,
    const float* __restrict__ stats, const float* __restrict__ gamma, const float* __restrict__ beta,
    u16* __restrict__ X1t)
{
    int b = blockIdx.z, mt = blockIdx.y * 64, nt = blockIdx.x * 64;
    __shared__ u16 tl[64][66];
    int t = threadIdx.x, col = t & 63;
    for (int r = 0; r < 64; r += 4) {
        int ml = r + (t >> 6), m = mt + ml;
        float gm = gamma[m] * stats[2 * m + 1];
        float bs = beta[m] - gm * stats[2 * m];
        long gi = ((long)b * 1024 + m) * 4096 + nt + col;
        tl[ml][col] = f2b(x[gi] + fmaf(gm, b2f(P[gi]), bs));
    }
    __syncthreads();
    for (int r = 0; r < 64; r += 4) {
        int nl = r + (t >> 6);
        X1t[((long)b * 4096 + nt + nl) * 1024 + mt + col] = tl[col][nl];
    }
}

// ----------------------------- BN stats over pixel-major [16384][2048] bf16 ---
// Each thread owns 8 contiguous features; per-block partials -> atomicAdd.
__global__ __launch_bounds__(256) void bn_stats_col(const u16* __restrict__ Xp, float* __restrict__ accum)
{
    const int t = threadIdx.x;
    const int f0 = t * 8;
    float s[8], ss[8];
#pragma unroll
    for (int u = 0; u < 8; u++) { s[u] = 0.f; ss[u] = 0.f; }
    const u16* base = Xp + (long)blockIdx.x * 128 * 2048;
    for (int r = 0; r < 128; r++) {
        uint4 uv = *(const uint4*)(base + (long)r * 2048 + f0);
        unsigned int wsa[4] = {uv.x, uv.y, uv.z, uv.w};
#pragma unroll
        for (int u = 0; u < 4; u++) {
            float v0 = b2f((u16)wsa[u]), v1 = b2f((u16)(wsa[u] >> 16));
            s[2*u] += v0;   ss[2*u]   += v0 * v0;
            s[2*u+1] += v1; ss[2*u+1] += v1 * v1;
        }
    }
#pragma unroll
    for (int u = 0; u < 8; u++) {
        atomicAdd(&accum[f0 + u], s[u]);
        atomicAdd(&accum[2048 + f0 + u], ss[u]);
    }
}

// --------------------------------- in-place relu(BN(.)) on pixel-major F1 ---
__global__ __launch_bounds__(256) void bn_relu_ip(u16* __restrict__ Xp, const float* __restrict__ accum,
    const float* __restrict__ gamma, const float* __restrict__ beta)
{
    long i = ((long)blockIdx.x * 256 + threadIdx.x) * 8;
    int f = (int)(i & 2047);
    uint4 uv = *(const uint4*)(Xp + i);
    unsigned int wsa[4] = {uv.x, uv.y, uv.z, uv.w};
    unsigned int ov[4];
#pragma unroll
    for (int u = 0; u < 4; u++) {
        unsigned int o = 0;
#pragma unroll
        for (int h = 0; h < 2; h++) {
            int ff = f + 2 * u + h;
            float S = accum[ff], SS = accum[2048 + ff];
            float mean = S * (1.f / 16384.f);
            float var = SS * (1.f / 16384.f) - mean * mean;
            float g = gamma[ff] * rsqrtf(var + 1e-5f);
            float bb = beta[ff] - g * mean;
            float xv = b2f((u16)(wsa[u] >> (16 * h)));
            float v = fmaxf(fmaf(g, xv, bb), 0.f);
            o |= ((unsigned int)f2b(v)) << (16 * h);
        }
        ov[u] = o;
    }
    *(uint4*)(Xp + i) = *(uint4*)ov;
}

// ---------------------- out[b][m][n] fp32 = X1t[b][n][m] + BN3(F2[b][m][n]) ---
__global__ __launch_bounds__(256) void final_tr(const u16* __restrict__ X1t, const u16* __restrict__ F2,
    const float* __restrict__ stats, const float* __restrict__ gamma, const float* __restrict__ beta,
    float* __restrict__ out)
{
    int b = blockIdx.z, mt = blockIdx.y * 64, nt = blockIdx.x * 64;
    __shared__ u16 tl[64][66];
    int t = threadIdx.x, col = t & 63;
    for (int r = 0; r < 64; r += 4) {
        int nl = r + (t >> 6);
        tl[nl][col] = X1t[((long)b * 4096 + nt + nl) * 1024 + mt + col];
    }
    __syncthreads();
    for (int r = 0; r < 64; r += 4) {
        int ml = r + (t >> 6), m = mt + ml;
        float gm = gamma[m] * stats[2 * m + 1];
        float bs = beta[m] - gm * stats[2 * m];
        long gi = ((long)b * 1024 + m) * 4096 + nt + col;
        out[gi] = b2f(tl[col][ml]) + fmaf(gm, b2f(F2[gi]), bs);
    }
}

extern "C" void kernel_launch(void* const* d_in, const int* in_sizes, int n_in,
                              void* d_out, int out_size, void* d_ws, size_t ws_size,
                              hipStream_t stream)
{
    const float* x     = (const float*)d_in[0];
    const float* wqkv  = (const float*)d_in[1];
    const float* wproj = (const float*)d_in[2];
    const float* wpe   = (const float*)d_in[3];
    const float* g_n   = (const float*)d_in[4];
    const float* b_n   = (const float*)d_in[5];
    const float* wf1   = (const float*)d_in[6];
    const float* g_f1  = (const float*)d_in[7];
    const float* b_f1  = (const float*)d_in[8];
    const float* wf2   = (const float*)d_in[9];
    const float* g_f2  = (const float*)d_in[10];
    const float* b_f2  = (const float*)d_in[11];
    float* out = (float*)d_out;
    char* ws = (char*)d_ws;

    // workspace layout, total 152,043,520 bytes (~145 MiB), slots aliased by
    // lifetime (verified: no producer/consumer address overlap):
    //   [0, 17.8M)      weights + stats (persistent)
    //   [17.8M,118.5M)  QKV -> {O2t, X1t}@17.8M + {P, F1p}@51.4M
    //   [118.5M,152.0M) Xt -> Oat -> F2
    u16*   Wq      = (u16*)(ws + 0);
    u16*   Wp      = (u16*)(ws + 6291456);
    u16*   W1      = (u16*)(ws + 8388608);
    u16*   W2      = (u16*)(ws + 12582912);
    float* Wpe_eff = (float*)(ws + 16777216);
    float* st1     = (float*)(ws + 17367040);
    float* accum2  = (float*)(ws + 17375232);   // 4096 floats (sums, sumsqs)
    float* st3     = (float*)(ws + 17391616);
    u16*   QKV = (u16*)(ws + 17825792);         // 100.7 MB
    u16*   O2t = (u16*)(ws + 17825792);         // 33.5 MB
    u16*   X1t = (u16*)(ws + 17825792);         // 33.5 MB
    u16*   P   = (u16*)(ws + 51380224);         // 33.5 MB
    u16*   F1p = (u16*)(ws + 51380224);         // 67 MB (pixel-major)
    u16*   Xt  = (u16*)(ws + 118489088);        // 33.5 MB
    u16*   Oat = (u16*)(ws + 118489088);        // 33.5 MB
    u16*   F2  = (u16*)(ws + 118489088);        // 33.5 MB

    zero_accum<<<16, 256, 0, stream>>>(accum2);
    build_weights<<<33344, 256, 0, stream>>>(wqkv, wproj, wf1, wf2, wpe, Wq, Wp, W1, W2, Wpe_eff);
    cast_tr<<<dim3(64, 16, 4), 256, 0, stream>>>(x, Xt);
    gemm_bt<false><<<dim3(32, 24, 4), 256, 0, stream>>>(Wq, Xt, QKV, 3072, 4096, 1024, 4096L * 1024, 3072L * 4096);
    attn_kernel<<<128, 256, 0, stream>>>(QKV, Oat);
    pe_kernel<<<dim3(16, 64, 4), 256, 0, stream>>>(Oat, Wpe_eff, O2t);
    gemm_bt<false><<<dim3(32, 8, 4), 256, 0, stream>>>(Wp, O2t, P, 1024, 4096, 1024, 4096L * 1024, 1024L * 4096);
    bn_stats<<<1024, 256, 0, stream>>>(P, st1, 1024);
    bn_add_tr<<<dim3(64, 16, 4), 256, 0, stream>>>(x, P, st1, g_n, b_n, X1t);
    gemm_bt<true><<<dim3(32, 16, 4), 256, 0, stream>>>(W1, X1t, F1p, 2048, 4096, 1024, 4096L * 1024, 4096L * 2048);
    bn_stats_col<<<128, 256, 0, stream>>>(F1p, accum2);
    bn_relu_ip<<<16384, 256, 0, stream>>>(F1p, accum2, g_f1, b_f1);
    gemm_bt<false><<<dim3(32, 8, 4), 256, 0, stream>>>(W2, F1p, F2, 1024, 4096, 2048, 4096L * 2048, 1024L * 4096);
    bn_stats<<<1024, 256, 0, stream>>>(F2, st3, 1024);
    final_tr<<<dim3(64, 16, 4), 256, 0, stream>>>(X1t, F2, st3, g_f2, b_f2, out);
}